// Round 1
// baseline (2763.792 us; speedup 1.0000x reference)
//
#include <hip/hip_runtime.h>
#include <math.h>

#define HW   9216      // 96*96
#define HDIM 96
#define WDIM 96
#define NIMG 8
#define CF   64
#define OFFC 144       // 2*DG*KK
#define MSKC 72        // DG*KK
#define OMC  216       // OFFC+MSKC

// ---------------------------------------------------------------------------
// Generic direct conv3x3, pad=1, stride=1. One block = 16x16 spatial tile,
// one image, OCB output channels. Input planes staged 4-at-a-time in LDS.
// Optionally applies sigmoid to out channels >= sig_from (offset-gen fusion).
// ---------------------------------------------------------------------------
template<int CIN, int OCB, bool SIG>
__global__ __launch_bounds__(256) void conv3x3_k(
    const float* __restrict__ in,    // [8, CIN, 96, 96]
    const float* __restrict__ wgt,   // [COUT, CIN, 3, 3]
    float* __restrict__ out,         // [8, COUT, 96, 96]
    int cout_total, int sig_from)
{
    const int tile = blockIdx.x;           // 0..35
    const int ocg  = blockIdx.y;
    const int n    = blockIdx.z;
    const int ty = threadIdx.x >> 4, tx = threadIdx.x & 15;
    const int oy = (tile / 6) * 16, ox = (tile % 6) * 16;

    __shared__ float lds[4][18 * 18];

    const float* inn = in + (size_t)n * CIN * HW;
    const int ocbase = ocg * OCB;

    float acc[OCB];
#pragma unroll
    for (int o = 0; o < OCB; ++o) acc[o] = 0.f;

    for (int cc = 0; cc < CIN; cc += 4) {
        __syncthreads();
        for (int j = threadIdx.x; j < 4 * 324; j += 256) {
            int p = j / 324, e = j - p * 324;
            int r = e / 18, c = e - r * 18;
            int y = oy + r - 1, x = ox + c - 1;
            float v = 0.f;
            if (y >= 0 && y < HDIM && x >= 0 && x < WDIM)
                v = inn[(size_t)(cc + p) * HW + y * WDIM + x];
            lds[p][e] = v;
        }
        __syncthreads();
#pragma unroll
        for (int p = 0; p < 4; ++p) {
            float v[9];
#pragma unroll
            for (int dy = 0; dy < 3; ++dy)
#pragma unroll
                for (int dx = 0; dx < 3; ++dx)
                    v[dy * 3 + dx] = lds[p][(ty + dy) * 18 + tx + dx];
            const float* wp = wgt + ((size_t)ocbase * CIN + (cc + p)) * 9;
#pragma unroll
            for (int o = 0; o < OCB; ++o) {
                const float* w9 = wp + (size_t)o * CIN * 9;
#pragma unroll
                for (int k = 0; k < 9; ++k)
                    acc[o] = fmaf(w9[k], v[k], acc[o]);
            }
        }
    }

    const int pix = (oy + ty) * WDIM + ox + tx;
#pragma unroll
    for (int o = 0; o < OCB; ++o) {
        float r = acc[o];
        if (SIG && (ocbase + o) >= sig_from)
            r = 1.f / (1.f + __expf(-r));
        out[((size_t)n * cout_total + ocbase + o) * HW + pix] = r;
    }
}

// ---------------------------------------------------------------------------
// Bottleneck conv3x3: 128 input channels = concat(burst[n], burst[0]).
// ---------------------------------------------------------------------------
template<int OCB>
__global__ __launch_bounds__(256) void bottleneck_k(
    const float* __restrict__ burst, // [8, 64, 96, 96]
    const float* __restrict__ wgt,   // [64, 128, 3, 3]
    float* __restrict__ out)         // [8, 64, 96, 96]
{
    const int tile = blockIdx.x;
    const int ocg  = blockIdx.y;
    const int n    = blockIdx.z;
    const int ty = threadIdx.x >> 4, tx = threadIdx.x & 15;
    const int oy = (tile / 6) * 16, ox = (tile % 6) * 16;

    __shared__ float lds[4][18 * 18];

    const int ocbase = ocg * OCB;
    float acc[OCB];
#pragma unroll
    for (int o = 0; o < OCB; ++o) acc[o] = 0.f;

    for (int cc = 0; cc < 128; cc += 4) {
        __syncthreads();
        for (int j = threadIdx.x; j < 4 * 324; j += 256) {
            int p = j / 324, e = j - p * 324;
            int r = e / 18, c = e - r * 18;
            int y = oy + r - 1, x = ox + c - 1;
            int ci = cc + p;
            const float* src = (ci < CF) ? burst + ((size_t)n * CF + ci) * HW
                                         : burst + (size_t)(ci - CF) * HW;
            float v = 0.f;
            if (y >= 0 && y < HDIM && x >= 0 && x < WDIM)
                v = src[y * WDIM + x];
            lds[p][e] = v;
        }
        __syncthreads();
#pragma unroll
        for (int p = 0; p < 4; ++p) {
            float v[9];
#pragma unroll
            for (int dy = 0; dy < 3; ++dy)
#pragma unroll
                for (int dx = 0; dx < 3; ++dx)
                    v[dy * 3 + dx] = lds[p][(ty + dy) * 18 + tx + dx];
            const float* wp = wgt + ((size_t)ocbase * 128 + (cc + p)) * 9;
#pragma unroll
            for (int o = 0; o < OCB; ++o) {
                const float* w9 = wp + (size_t)o * 128 * 9;
#pragma unroll
                for (int k = 0; k < 9; ++k)
                    acc[o] = fmaf(w9[k], v[k], acc[o]);
            }
        }
    }

    const int pix = (oy + ty) * WDIM + ox + tx;
#pragma unroll
    for (int o = 0; o < OCB; ++o)
        out[((size_t)n * CF + ocbase + o) * HW + pix] = acc[o];
}

// ---------------------------------------------------------------------------
// Modulated deformable conv (torchvision semantics), DG=8 groups, Cg=8.
// One thread per output pixel per group; computes the group's 8 out channels.
// ---------------------------------------------------------------------------
__global__ __launch_bounds__(256) void deform_k(
    const float* __restrict__ x,     // [8, 64, 96, 96]
    const float* __restrict__ om,    // [8, 216, 96, 96] (mask already sigmoid)
    const float* __restrict__ wgt,   // [64, 8, 3, 3]
    const float* __restrict__ bias,  // [64]
    float* __restrict__ out)         // [8, 64, 96, 96]
{
    const int tile = blockIdx.x;
    const int g    = blockIdx.y;
    const int n    = blockIdx.z;

    __shared__ float lw[576];        // group's weights: [8 out][8 in][9]
    for (int j = threadIdx.x; j < 576; j += 256)
        lw[j] = wgt[(size_t)g * 576 + j];
    __syncthreads();

    const int ty = threadIdx.x >> 4, tx = threadIdx.x & 15;
    const int h  = (tile / 6) * 16 + ty;
    const int wx = (tile % 6) * 16 + tx;
    const int pix = h * WDIM + wx;

    const float* ob = om + (size_t)n * OMC * HW;
    const float* xb = x + ((size_t)n * CF + g * 8) * HW;

    float acc[8];
#pragma unroll
    for (int o = 0; o < 8; ++o) acc[o] = 0.f;

#pragma unroll
    for (int k = 0; k < 9; ++k) {
        float dy = ob[(size_t)(g * 18 + 2 * k    ) * HW + pix];
        float dx = ob[(size_t)(g * 18 + 2 * k + 1) * HW + pix];
        float m  = ob[(size_t)(OFFC + g * 9 + k  ) * HW + pix];

        float py = dy + (float)(k / 3 - 1) + (float)h;
        float px = dx + (float)(k % 3 - 1) + (float)wx;
        float y0f = floorf(py), x0f = floorf(px);
        float ly = py - y0f, lx = px - x0f;
        int y0 = (int)y0f, x0 = (int)x0f;
        int y1 = y0 + 1,   x1 = x0 + 1;

        bool vy0 = (y0 >= 0) && (y0 < HDIM);
        bool vy1 = (y1 >= 0) && (y1 < HDIM);
        bool vx0 = (x0 >= 0) && (x0 < WDIM);
        bool vx1 = (x1 >= 0) && (x1 < WDIM);

        float w00 = (vy0 && vx0) ? (1.f - ly) * (1.f - lx) : 0.f;
        float w01 = (vy0 && vx1) ? (1.f - ly) * lx         : 0.f;
        float w10 = (vy1 && vx0) ? ly * (1.f - lx)         : 0.f;
        float w11 = (vy1 && vx1) ? ly * lx                 : 0.f;

        int y0c = min(max(y0, 0), HDIM - 1), y1c = min(max(y1, 0), HDIM - 1);
        int x0c = min(max(x0, 0), WDIM - 1), x1c = min(max(x1, 0), WDIM - 1);
        int i00 = y0c * WDIM + x0c, i01 = y0c * WDIM + x1c;
        int i10 = y1c * WDIM + x0c, i11 = y1c * WDIM + x1c;

#pragma unroll
        for (int c = 0; c < 8; ++c) {
            const float* xp = xb + (size_t)c * HW;
            float v = w00 * xp[i00] + w01 * xp[i01]
                    + w10 * xp[i10] + w11 * xp[i11];
            v *= m;
#pragma unroll
            for (int o = 0; o < 8; ++o)
                acc[o] = fmaf(lw[o * 72 + c * 9 + k], v, acc[o]);
        }
    }

#pragma unroll
    for (int o = 0; o < 8; ++o)
        out[((size_t)n * CF + g * 8 + o) * HW + pix] = acc[o] + bias[g * 8 + o];
}

// ---------------------------------------------------------------------------
extern "C" void kernel_launch(void* const* d_in, const int* in_sizes, int n_in,
                              void* d_out, int out_size, void* d_ws, size_t ws_size,
                              hipStream_t stream) {
    const float* burst = (const float*)d_in[0];
    const float* bw    = (const float*)d_in[1];

    // setup_inputs() dict order is interleaved (off_w1, def_w1, def_b1, ...);
    // dispatch on sizes so a signature-ordered harness also works.
    const float* ow[4]; const float* dw[4]; const float* db[4];
    bool interleaved = (in_sizes[3] == 64 * 8 * 9);   // def_w right after off_w1
    for (int i = 0; i < 4; ++i) {
        if (interleaved) {
            ow[i] = (const float*)d_in[2 + 3 * i];
            dw[i] = (const float*)d_in[3 + 3 * i];
            db[i] = (const float*)d_in[4 + 3 * i];
        } else {
            ow[i] = (const float*)d_in[2 + i];
            dw[i] = (const float*)d_in[6 + i];
            db[i] = (const float*)d_in[10 + i];
        }
    }

    float* out  = (float*)d_out;
    float* fA   = (float*)d_ws;                        // 8*64*9216 floats
    float* offm = fA + (size_t)NIMG * CF * HW;         // 8*216*9216 floats

    dim3 blk(256);

    // bottleneck: concat(burst, ref) -> out  (out fully overwritten first)
    bottleneck_k<16><<<dim3(36, 4, 8), blk, 0, stream>>>(burst, bw, out);

    // ping-pong: out -> fA -> out -> fA -> out
    float* cur = out;
    float* nxt = fA;
    for (int i = 0; i < 4; ++i) {
        conv3x3_k<64, 24, true><<<dim3(36, 9, 8), blk, 0, stream>>>(
            cur, ow[i], offm, OMC, OFFC);
        float* dst = (i == 3) ? out : nxt;
        deform_k<<<dim3(36, 8, 8), blk, 0, stream>>>(
            cur, offm, dw[i], db[i], dst);
        nxt = cur;
        cur = dst;
    }
}

// Round 2
// 1288.846 us; speedup vs baseline: 2.1444x; 2.1444x over previous
//
#include <hip/hip_runtime.h>
#include <math.h>

#define HW    9216
#define HDIM  96
#define WDIM  96
#define NIMG  8
#define CF    64
#define OFFCH 144
#define MSKCH 72

typedef unsigned short u16;
typedef unsigned int   u32;
typedef __attribute__((ext_vector_type(8))) short s16x8;
typedef __attribute__((ext_vector_type(4))) float f32x4;

// ---- bf16 helpers -----------------------------------------------------------
__device__ inline u16 f2bf_rne(float v) {
    u32 u = __float_as_uint(v);
    u += 0x7fffu + ((u >> 16) & 1u);
    return (u16)(u >> 16);
}
__device__ inline float bf2f(u16 h) { return __uint_as_float(((u32)h) << 16); }
__device__ inline void split_hilo(float v, u16& h, u16& l) {
    h = f2bf_rne(v);
    float r = v - bf2f(h);          // exact (Dekker split)
    l = f2bf_rne(r);
}

// ---- weight prepack: OIHW fp32 -> [oc][tap][ci] bf16 hi/lo ------------------
// bneck: 64x128x9 at wp+0 (hi), +73728 (lo).
// layer i: 224(oc,216 used)x9x64 at wp+147456+i*258048 (hi), +129024 (lo).
__global__ void pack_w_k(const float* __restrict__ bw,
                         const float* __restrict__ ow0, const float* __restrict__ ow1,
                         const float* __restrict__ ow2, const float* __restrict__ ow3,
                         u16* __restrict__ wp)
{
    const float* ows[4] = {ow0, ow1, ow2, ow3};
    int total = 73728 + 4 * 124416;
    for (int j = blockIdx.x * blockDim.x + threadIdx.x; j < total;
         j += gridDim.x * blockDim.x) {
        float v; size_t dst;
        if (j < 73728) {                      // bneck  src[oc][ci][tap]
            int oc = j / 1152, r = j % 1152, ci = r / 9, tap = r % 9;
            v = bw[j];
            dst = (size_t)(oc * 9 + tap) * 128 + ci;
            u16 h, l; split_hilo(v, h, l);
            wp[dst] = h; wp[73728 + dst] = l;
        } else {
            int k = j - 73728;
            int layer = k / 124416, r = k % 124416;
            int oc = r / 576, r3 = r % 576, ci = r3 / 9, tap = r3 % 9;
            v = ows[layer][r];
            size_t base = 147456 + (size_t)layer * 258048;
            dst = base + (size_t)(oc * 9 + tap) * 64 + ci;
            u16 h, l; split_hilo(v, h, l);
            wp[dst] = h; wp[dst + 129024] = l;
        }
    }
}

// ---- build concat(burst[n], burst[0]) as NHWC bf16 hi/lo [8][9216][128] -----
__global__ __launch_bounds__(256) void prep_cat_k(
    const float* __restrict__ burst, u16* __restrict__ ch, u16* __restrict__ cl)
{
    const int n = blockIdx.y;
    const int lane = threadIdx.x & 63, warp = threadIdx.x >> 6;
    const int pix0 = blockIdx.x * 256 + warp * 64;
    const float* cur = burst + ((size_t)n * CF + lane) * HW;
    const float* ref = burst + (size_t)lane * HW;
    for (int p = 0; p < 64; ++p) {
        int pix = pix0 + p;
        float v1 = cur[pix], v2 = ref[pix];
        u16 h1, l1, h2, l2;
        split_hilo(v1, h1, l1); split_hilo(v2, h2, l2);
        size_t b = ((size_t)n * HW + pix) * 128;
        ch[b + lane] = h1; ch[b + 64 + lane] = h2;
        cl[b + lane] = l1; cl[b + 64 + lane] = l2;
    }
}

// ---- convert d_out fp32 NCHW -> feat NHWC bf16 hi/lo ------------------------
__global__ __launch_bounds__(256) void convert_k(
    const float* __restrict__ src, u16* __restrict__ fh, u16* __restrict__ fl)
{
    const int n = blockIdx.y;
    const int lane = threadIdx.x & 63, warp = threadIdx.x >> 6;
    const int pix0 = blockIdx.x * 256 + warp * 64;
    const float* sp = src + ((size_t)n * CF + lane) * HW;
    for (int p = 0; p < 64; ++p) {
        int pix = pix0 + p;
        float v = sp[pix];
        u16 h, l; split_hilo(v, h, l);
        size_t b = ((size_t)n * HW + pix) * CF;
        fh[b + lane] = h; fl[b + lane] = l;
    }
}

// ---- MFMA implicit-GEMM conv3x3 ---------------------------------------------
// Block: 16x16 spatial tile x (up to) 64 oc. 4 waves, wave w owns rows 4w..4w+3.
// K ordered tap-major, ci-inner; ci chunked by 32 through an LDS halo tile.
// MODE 0: bneck epilogue (write feat NHWC hi/lo).
// MODE 1: offset epilogue (oc<144 -> offs fp32 NCHW; 144..215 -> sigmoid mask bf16).
template<int CIN, int MODE>
__global__ __launch_bounds__(256) void conv_mfma_k(
    const u16* __restrict__ in_hi, const u16* __restrict__ in_lo,
    const u16* __restrict__ w_hi,  const u16* __restrict__ w_lo,
    float* __restrict__ offs_out,  u16* __restrict__ mask_out,
    u16* __restrict__ out_hi,      u16* __restrict__ out_lo,
    int nOct)
{
    __shared__ __align__(16) u16 lds_hi[324 * 40];
    __shared__ __align__(16) u16 lds_lo[324 * 40];

    const int tid = threadIdx.x;
    const int wv = tid >> 6, lane = tid & 63;
    const int lx = lane & 15, lg = lane >> 4;
    const int oy = (blockIdx.x / 6) * 16, ox = (blockIdx.x % 6) * 16;
    const int ocg = blockIdx.y, n = blockIdx.z;

    f32x4 acc[4][4];
#pragma unroll
    for (int t = 0; t < 4; ++t)
#pragma unroll
        for (int r = 0; r < 4; ++r)
            acc[t][r] = (f32x4){0.f, 0.f, 0.f, 0.f};

    for (int ch = 0; ch < CIN / 32; ++ch) {
        __syncthreads();
        // stage 18x18 halo x 32ci, hi+lo, 16B units
        for (int u = tid; u < 2592; u += 256) {
            int q = u & 3, half = (u >> 2) & 1, pos = u >> 3;
            int yy = pos / 18, xx = pos - yy * 18;
            int gy = oy + yy - 1, gx = ox + xx - 1;
            uint4 val; val.x = val.y = val.z = val.w = 0u;
            if (gy >= 0 && gy < HDIM && gx >= 0 && gx < WDIM) {
                const u16* src = (half ? in_lo : in_hi) +
                    ((size_t)(n * HW + gy * WDIM + gx) * CIN + ch * 32 + q * 8);
                val = *(const uint4*)src;
            }
            u16* dst = (half ? lds_lo : lds_hi) + pos * 40 + q * 8;
            *(uint4*)dst = val;
        }
        __syncthreads();

        for (int tap = 0; tap < 9; ++tap) {
            int ky = tap / 3, kx = tap - ky * 3;
            s16x8 ah[4], al[4];
#pragma unroll
            for (int t = 0; t < 4; ++t) {
                int oct = ocg * 4 + t;
                if (oct < nOct) {
                    int oc = oct * 16 + lx;
                    size_t idx = ((size_t)(oc * 9 + tap) * CIN) + ch * 32 + lg * 8;
                    ah[t] = *(const s16x8*)(w_hi + idx);
                    al[t] = *(const s16x8*)(w_lo + idx);
                }
            }
            s16x8 bh[4], bl[4];
#pragma unroll
            for (int r = 0; r < 4; ++r) {
                int py = wv * 4 + r;
                int off = ((py + ky) * 18 + (lx + kx)) * 40 + lg * 8;
                bh[r] = *(const s16x8*)(lds_hi + off);
                bl[r] = *(const s16x8*)(lds_lo + off);
            }
#pragma unroll
            for (int t = 0; t < 4; ++t) {
                if (ocg * 4 + t >= nOct) continue;
#pragma unroll
                for (int r = 0; r < 4; ++r) {
                    acc[t][r] = __builtin_amdgcn_mfma_f32_16x16x32_bf16(ah[t], bh[r], acc[t][r], 0, 0, 0);
                    acc[t][r] = __builtin_amdgcn_mfma_f32_16x16x32_bf16(ah[t], bl[r], acc[t][r], 0, 0, 0);
                    acc[t][r] = __builtin_amdgcn_mfma_f32_16x16x32_bf16(al[t], bh[r], acc[t][r], 0, 0, 0);
                }
            }
        }
    }

    // epilogue: D row = oc_local = lg*4 + v, col = pixel = lx
#pragma unroll
    for (int t = 0; t < 4; ++t) {
        if (ocg * 4 + t >= nOct) continue;
#pragma unroll
        for (int r = 0; r < 4; ++r) {
            int y = oy + wv * 4 + r;
            int pix = y * WDIM + ox + lx;
            if (MODE == 0) {
                u16 h[4], l[4];
#pragma unroll
                for (int v = 0; v < 4; ++v) split_hilo(acc[t][r][v], h[v], l[v]);
                size_t b = ((size_t)(n * HW + pix)) * CF + t * 16 + lg * 4;
                uint2 hv, lv;
                hv.x = (u32)h[0] | ((u32)h[1] << 16); hv.y = (u32)h[2] | ((u32)h[3] << 16);
                lv.x = (u32)l[0] | ((u32)l[1] << 16); lv.y = (u32)l[2] | ((u32)l[3] << 16);
                *(uint2*)(out_hi + b) = hv;
                *(uint2*)(out_lo + b) = lv;
            } else {
#pragma unroll
                for (int v = 0; v < 4; ++v) {
                    int oc = (ocg * 4 + t) * 16 + lg * 4 + v;
                    float val = acc[t][r][v];
                    if (oc < OFFCH) {
                        offs_out[((size_t)n * OFFCH + oc) * HW + pix] = val;
                    } else if (oc < OFFCH + MSKCH) {
                        float s = 1.f / (1.f + __expf(-val));
                        mask_out[((size_t)n * MSKCH + (oc - OFFCH)) * HW + pix] = f2bf_rne(s);
                    }
                }
            }
        }
    }
}

// ---- modulated deformable conv, feat from NHWC bf16 hi/lo -------------------
struct U4 { u32 a0, a1, a2, a3; };
__device__ inline u32 getw(const U4& u, int i) {
    return i == 0 ? u.a0 : i == 1 ? u.a1 : i == 2 ? u.a2 : u.a3;
}
__device__ inline float f_at(const U4& u, int j) {
    u32 w = getw(u, j >> 1);
    u32 bits = (j & 1) ? (w & 0xffff0000u) : (w << 16);
    return __uint_as_float(bits);
}

__global__ __launch_bounds__(256) void deform_k(
    const u16* __restrict__ fh, const u16* __restrict__ fl,
    const float* __restrict__ offs, const u16* __restrict__ mask,
    const float* __restrict__ wgt, const float* __restrict__ bias,
    float* __restrict__ out)
{
    const int tile = blockIdx.x;
    const int g    = blockIdx.y;
    const int n    = blockIdx.z;

    __shared__ float lw[576];
    for (int j = threadIdx.x; j < 576; j += 256)
        lw[j] = wgt[(size_t)g * 576 + j];
    __syncthreads();

    const int ty = threadIdx.x >> 4, tx = threadIdx.x & 15;
    const int h  = (tile / 6) * 16 + ty;
    const int wx = (tile % 6) * 16 + tx;
    const int pix = h * WDIM + wx;

    const float* ob = offs + (size_t)n * OFFCH * HW;
    const u16*   mb = mask + (size_t)n * MSKCH * HW;
    const size_t fbase = (size_t)n * HW * CF + g * 8;

    float acc[8];
#pragma unroll
    for (int o = 0; o < 8; ++o) acc[o] = 0.f;

#pragma unroll
    for (int k = 0; k < 9; ++k) {
        float dy = ob[(size_t)(g * 18 + 2 * k    ) * HW + pix];
        float dx = ob[(size_t)(g * 18 + 2 * k + 1) * HW + pix];
        float m  = bf2f(mb[(size_t)(g * 9 + k) * HW + pix]);

        float py = dy + (float)(k / 3 - 1) + (float)h;
        float px = dx + (float)(k % 3 - 1) + (float)wx;
        float y0f = floorf(py), x0f = floorf(px);
        float ly = py - y0f, lx = px - x0f;
        int y0 = (int)y0f, x0 = (int)x0f;
        int y1 = y0 + 1,   x1 = x0 + 1;

        bool vy0 = (y0 >= 0) && (y0 < HDIM);
        bool vy1 = (y1 >= 0) && (y1 < HDIM);
        bool vx0 = (x0 >= 0) && (x0 < WDIM);
        bool vx1 = (x1 >= 0) && (x1 < WDIM);

        float w00 = (vy0 && vx0) ? (1.f - ly) * (1.f - lx) : 0.f;
        float w01 = (vy0 && vx1) ? (1.f - ly) * lx         : 0.f;
        float w10 = (vy1 && vx0) ? ly * (1.f - lx)         : 0.f;
        float w11 = (vy1 && vx1) ? ly * lx                 : 0.f;

        int y0c = min(max(y0, 0), HDIM - 1), y1c = min(max(y1, 0), HDIM - 1);
        int x0c = min(max(x0, 0), WDIM - 1), x1c = min(max(x1, 0), WDIM - 1);
        size_t i00 = fbase + (size_t)(y0c * WDIM + x0c) * CF;
        size_t i01 = fbase + (size_t)(y0c * WDIM + x1c) * CF;
        size_t i10 = fbase + (size_t)(y1c * WDIM + x0c) * CF;
        size_t i11 = fbase + (size_t)(y1c * WDIM + x1c) * CF;

        U4 H00 = *(const U4*)(fh + i00), L00 = *(const U4*)(fl + i00);
        U4 H01 = *(const U4*)(fh + i01), L01 = *(const U4*)(fl + i01);
        U4 H10 = *(const U4*)(fh + i10), L10 = *(const U4*)(fl + i10);
        U4 H11 = *(const U4*)(fh + i11), L11 = *(const U4*)(fl + i11);

#pragma unroll
        for (int c = 0; c < 8; ++c) {
            float v = w00 * (f_at(H00, c) + f_at(L00, c));
            v = fmaf(w01, f_at(H01, c) + f_at(L01, c), v);
            v = fmaf(w10, f_at(H10, c) + f_at(L10, c), v);
            v = fmaf(w11, f_at(H11, c) + f_at(L11, c), v);
            v *= m;
#pragma unroll
            for (int o = 0; o < 8; ++o)
                acc[o] = fmaf(lw[o * 72 + c * 9 + k], v, acc[o]);
        }
    }

#pragma unroll
    for (int o = 0; o < 8; ++o)
        out[((size_t)n * CF + g * 8 + o) * HW + pix] = acc[o] + bias[g * 8 + o];
}

// ---------------------------------------------------------------------------
extern "C" void kernel_launch(void* const* d_in, const int* in_sizes, int n_in,
                              void* d_out, int out_size, void* d_ws, size_t ws_size,
                              hipStream_t stream) {
    const float* burst = (const float*)d_in[0];
    const float* bw    = (const float*)d_in[1];

    const float* ow[4]; const float* dw[4]; const float* db[4];
    bool interleaved = (in_sizes[3] == 64 * 8 * 9);
    for (int i = 0; i < 4; ++i) {
        if (interleaved) {
            ow[i] = (const float*)d_in[2 + 3 * i];
            dw[i] = (const float*)d_in[3 + 3 * i];
            db[i] = (const float*)d_in[4 + 3 * i];
        } else {
            ow[i] = (const float*)d_in[2 + i];
            dw[i] = (const float*)d_in[6 + i];
            db[i] = (const float*)d_in[10 + i];
        }
    }

    float* out = (float*)d_out;

    // workspace layout (74.3 MB, < 82.6 MB proven in round 1)
    float* offs   = (float*)d_ws;                       // 10,616,832 f32
    u16*   mask   = (u16*)(offs + 10616832);            //  5,308,416 bf16
    u16*   feat_h = mask + 5308416;                     //  4,718,592 bf16
    u16*   feat_l = feat_h + 4718592;                   //  4,718,592 bf16
    u16*   wp     = feat_l + 4718592;                   //  1,179,648 bf16
    u16*   cat_h  = (u16*)d_ws;                         // alias over offs/mask
    u16*   cat_l  = cat_h + (size_t)NIMG * HW * 128;

    const u16* wp_bh = wp;
    const u16* wp_bl = wp + 73728;
    const u16* wp_oh[4], * wp_ol[4];
    for (int i = 0; i < 4; ++i) {
        wp_oh[i] = wp + 147456 + (size_t)i * 258048;
        wp_ol[i] = wp_oh[i] + 129024;
    }

    pack_w_k<<<dim3(1024), dim3(256), 0, stream>>>(bw, ow[0], ow[1], ow[2], ow[3], wp);
    prep_cat_k<<<dim3(36, NIMG), dim3(256), 0, stream>>>(burst, cat_h, cat_l);

    // bottleneck: cat -> feat hi/lo (NHWC)
    conv_mfma_k<128, 0><<<dim3(36, 1, NIMG), dim3(256), 0, stream>>>(
        cat_h, cat_l, wp_bh, wp_bl, nullptr, nullptr, feat_h, feat_l, 4);

    for (int i = 0; i < 4; ++i) {
        conv_mfma_k<64, 1><<<dim3(36, 4, NIMG), dim3(256), 0, stream>>>(
            feat_h, feat_l, wp_oh[i], wp_ol[i], offs, mask, nullptr, nullptr, 14);
        deform_k<<<dim3(36, 8, NIMG), dim3(256), 0, stream>>>(
            feat_h, feat_l, offs, mask, dw[i], db[i], out);
        if (i < 3)
            convert_k<<<dim3(36, NIMG), dim3(256), 0, stream>>>(out, feat_h, feat_l);
    }
}

// Round 3
// 970.688 us; speedup vs baseline: 2.8472x; 1.3278x over previous
//
#include <hip/hip_runtime.h>
#include <math.h>

#define HW    9216
#define HDIM  96
#define WDIM  96
#define NIMG  8
#define CF    64
#define OFFCH 144
#define MSKCH 72

typedef unsigned short u16;
typedef unsigned int   u32;
typedef _Float16 f16;
typedef __attribute__((ext_vector_type(8))) _Float16 f16x8;
typedef __attribute__((ext_vector_type(4))) float f32x4;

// ---- fp16 hi/scaled-lo helpers ---------------------------------------------
// v ~= hi + lo/2048, hi = fp16(v), lo = fp16((v-hi)*2048).
// Scaling keeps weight-lo (~2.4e-5) out of fp16 subnormal range.
__device__ inline u16 f16b(f16 h){ u16 r; __builtin_memcpy(&r, &h, 2); return r; }
__device__ inline f16 b16f(u16 b){ f16 h; __builtin_memcpy(&h, &b, 2); return h; }
__device__ inline void split16(float v, u16& hb, u16& lb){
    f16 h = (f16)v;
    f16 l = (f16)((v - (float)h) * 2048.0f);
    hb = f16b(h); lb = f16b(l);
}

// ---- weight prepack ---------------------------------------------------------
// wp (u16): bneck hi [64*9*128] @0, lo @73728;
//           layer i: hi [224*9*64] @147456+i*258048, lo @+129024 (oc>=216 zeroed)
// dwp (f32): deform weights transposed [layer][g][k][c][o] (4*8*576)
__global__ void pack_w_k(const float* __restrict__ bw,
                         const float* __restrict__ ow0, const float* __restrict__ ow1,
                         const float* __restrict__ ow2, const float* __restrict__ ow3,
                         const float* __restrict__ dw0, const float* __restrict__ dw1,
                         const float* __restrict__ dw2, const float* __restrict__ dw3,
                         u16* __restrict__ wp, float* __restrict__ dwp)
{
    const float* ows[4] = {ow0, ow1, ow2, ow3};
    const float* dws[4] = {dw0, dw1, dw2, dw3};
    int total = 73728 + 4 * 124416;
    for (int j = blockIdx.x * blockDim.x + threadIdx.x; j < total;
         j += gridDim.x * blockDim.x) {
        if (j < 73728) {                      // bneck src [oc][ci][tap]
            int oc = j / 1152, r = j % 1152, ci = r / 9, tap = r % 9;
            u16 h, l; split16(bw[j], h, l);
            size_t dst = (size_t)(oc * 9 + tap) * 128 + ci;
            wp[dst] = h; wp[73728 + dst] = l;
        } else {
            int k = j - 73728;
            int layer = k / 124416, r = k % 124416;
            int oc = r / 576, r3 = r % 576, ci = r3 / 9, tap = r3 % 9;
            u16 h, l; split16(ows[layer][r], h, l);
            size_t dst = 147456 + (size_t)layer * 258048 + (size_t)(oc * 9 + tap) * 64 + ci;
            wp[dst] = h; wp[dst + 129024] = l;
        }
    }
    // zero pad rows oc 216..223 of each offset layer (both halves)
    for (int j = blockIdx.x * blockDim.x + threadIdx.x; j < 4 * 4608;
         j += gridDim.x * blockDim.x) {
        int layer = j / 4608, e = j % 4608;
        size_t base = 147456 + (size_t)layer * 258048;
        wp[base + 124416 + e] = 0;
        wp[base + 129024 + 124416 + e] = 0;
    }
    // deform weights: src [oc=g*8+o][c][k] -> dwp[(layer*8+g)*576 + (k*8+c)*8 + o]
    for (int j = blockIdx.x * blockDim.x + threadIdx.x; j < 4 * 8 * 576;
         j += gridDim.x * blockDim.x) {
        int layer = j / 4608, r = j % 4608, g = r / 576, e = r % 576;
        int kk = e / 64, c = (e / 8) % 8, o = e % 8;
        dwp[j] = dws[layer][(size_t)(g * 8 + o) * 72 + c * 9 + kk];
    }
}

// ---- build concat(burst[n], burst[0]) NHWC fp16 hi/lo [8][9216][128] --------
__global__ __launch_bounds__(256) void prep_cat_k(
    const float* __restrict__ burst, u16* __restrict__ ch, u16* __restrict__ cl)
{
    const int n = blockIdx.y;
    const int lane = threadIdx.x & 63, warp = threadIdx.x >> 6;
    const int pix0 = blockIdx.x * 256 + warp * 64;
    const float* cur = burst + ((size_t)n * CF + lane) * HW;
    const float* ref = burst + (size_t)lane * HW;
    for (int p = 0; p < 64; ++p) {
        int pix = pix0 + p;
        u16 h1, l1, h2, l2;
        split16(cur[pix], h1, l1); split16(ref[pix], h2, l2);
        size_t b = ((size_t)n * HW + pix) * 128;
        ch[b + lane] = h1; ch[b + 64 + lane] = h2;
        cl[b + lane] = l1; cl[b + 64 + lane] = l2;
    }
}

// ---- MFMA implicit-GEMM conv3x3 (fp16 hi/scaled-lo, dual accumulators) ------
// Block: 16x16 spatial tile x 32 oc (2 oct). 4 waves; wave w owns rows 4w..4w+3.
// acc1 = Ah*Bh ; acc2 = Ah*Bl' + Al'*Bh (both scaled 2048) ; out = acc1+acc2/2048
template<int CIN, int MODE>
__global__ __launch_bounds__(256, 3) void conv_mfma_k(
    const u16* __restrict__ in_hi, const u16* __restrict__ in_lo,
    const u16* __restrict__ w_hi,  const u16* __restrict__ w_lo,
    float* __restrict__ offs_out,  u16* __restrict__ mask_out,
    u16* __restrict__ out_hi,      u16* __restrict__ out_lo)
{
    __shared__ __align__(16) u16 lds_hi[324 * 40];
    __shared__ __align__(16) u16 lds_lo[324 * 40];

    const int tid = threadIdx.x;
    const int wv = tid >> 6, lane = tid & 63;
    const int lx = lane & 15, lg = lane >> 4;
    const int oy = (blockIdx.x / 6) * 16, ox = (blockIdx.x % 6) * 16;
    const int ocg = blockIdx.y, n = blockIdx.z;

    f32x4 acc1[2][4], acc2[2][4];
#pragma unroll
    for (int t = 0; t < 2; ++t)
#pragma unroll
        for (int r = 0; r < 4; ++r) {
            acc1[t][r] = (f32x4){0.f, 0.f, 0.f, 0.f};
            acc2[t][r] = (f32x4){0.f, 0.f, 0.f, 0.f};
        }

    for (int chk = 0; chk < CIN / 32; ++chk) {
        __syncthreads();
        // stage 18x18 halo x 32ci, hi+lo, 16B units
        for (int u = tid; u < 2592; u += 256) {
            int q = u & 3, half = (u >> 2) & 1, pos = u >> 3;
            int yy = pos / 18, xx = pos - yy * 18;
            int gy = oy + yy - 1, gx = ox + xx - 1;
            uint4 val; val.x = val.y = val.z = val.w = 0u;
            if (gy >= 0 && gy < HDIM && gx >= 0 && gx < WDIM) {
                const u16* src = (half ? in_lo : in_hi) +
                    ((size_t)(n * HW + gy * WDIM + gx) * CIN + chk * 32 + q * 8);
                val = *(const uint4*)src;
            }
            u16* dst = (half ? lds_lo : lds_hi) + pos * 40 + q * 8;
            *(uint4*)dst = val;
        }
        __syncthreads();

        for (int tap = 0; tap < 9; ++tap) {
            int ky = tap / 3, kx = tap - ky * 3;
            f16x8 ah[2], al[2];
#pragma unroll
            for (int t = 0; t < 2; ++t) {
                int oc = ocg * 32 + t * 16 + lx;
                size_t idx = ((size_t)(oc * 9 + tap) * CIN) + chk * 32 + lg * 8;
                ah[t] = *(const f16x8*)(w_hi + idx);
                al[t] = *(const f16x8*)(w_lo + idx);
            }
            f16x8 bh[4], bl[4];
#pragma unroll
            for (int r = 0; r < 4; ++r) {
                int py = wv * 4 + r;
                int off = ((py + ky) * 18 + (lx + kx)) * 40 + lg * 8;
                bh[r] = *(const f16x8*)(lds_hi + off);
                bl[r] = *(const f16x8*)(lds_lo + off);
            }
#pragma unroll
            for (int t = 0; t < 2; ++t)
#pragma unroll
                for (int r = 0; r < 4; ++r) {
                    acc1[t][r] = __builtin_amdgcn_mfma_f32_16x16x32_f16(ah[t], bh[r], acc1[t][r], 0, 0, 0);
                    acc2[t][r] = __builtin_amdgcn_mfma_f32_16x16x32_f16(ah[t], bl[r], acc2[t][r], 0, 0, 0);
                    acc2[t][r] = __builtin_amdgcn_mfma_f32_16x16x32_f16(al[t], bh[r], acc2[t][r], 0, 0, 0);
                }
        }
    }

    // epilogue: D col = pixel = lx, row = oc_local = lg*4 + v
#pragma unroll
    for (int t = 0; t < 2; ++t)
#pragma unroll
        for (int r = 0; r < 4; ++r) {
            int y = oy + wv * 4 + r;
            int pix = y * WDIM + ox + lx;
            if (MODE == 0) {
                u16 h[4], l[4];
#pragma unroll
                for (int v = 0; v < 4; ++v) {
                    float val = acc1[t][r][v] + acc2[t][r][v] * (1.0f / 2048.0f);
                    split16(val, h[v], l[v]);
                }
                size_t b = ((size_t)(n * HW + pix)) * CF + ocg * 32 + t * 16 + lg * 4;
                uint2 hv, lv;
                hv.x = (u32)h[0] | ((u32)h[1] << 16); hv.y = (u32)h[2] | ((u32)h[3] << 16);
                lv.x = (u32)l[0] | ((u32)l[1] << 16); lv.y = (u32)l[2] | ((u32)l[3] << 16);
                *(uint2*)(out_hi + b) = hv;
                *(uint2*)(out_lo + b) = lv;
            } else {
#pragma unroll
                for (int v = 0; v < 4; ++v) {
                    int oc = ocg * 32 + t * 16 + lg * 4 + v;
                    float val = acc1[t][r][v] + acc2[t][r][v] * (1.0f / 2048.0f);
                    if (oc < OFFCH) {
                        offs_out[((size_t)n * OFFCH + oc) * HW + pix] = val;
                    } else if (oc < OFFCH + MSKCH) {
                        float s = 1.f / (1.f + __expf(-val));
                        mask_out[((size_t)n * MSKCH + (oc - OFFCH)) * HW + pix] = f16b((f16)s);
                    }
                }
            }
        }
}

// ---- modulated deformable conv; gathers fp16-hi feat (NHWC) -----------------
// One thread per (pixel, group); weights via wave-uniform scalar loads.
template<int LAST>
__global__ __launch_bounds__(256, 4) void deform_k(
    const u16* __restrict__ fh,   const float* __restrict__ offs,
    const u16* __restrict__ mask, const float* __restrict__ wgtp, // [g][k][c][o]
    const float* __restrict__ bias,
    u16* __restrict__ out_h, u16* __restrict__ out_l, float* __restrict__ out32)
{
    const int tile = blockIdx.x;
    const int g    = blockIdx.y;
    const int n    = blockIdx.z;

    const int ty = threadIdx.x >> 4, tx = threadIdx.x & 15;
    const int h  = (tile / 6) * 16 + ty;
    const int wx = (tile % 6) * 16 + tx;
    const int pix = h * WDIM + wx;

    const float* wg = wgtp + (size_t)g * 576;   // wave-uniform
    const float* ob = offs + (size_t)n * OFFCH * HW;
    const u16*   mb = mask + (size_t)n * MSKCH * HW;
    const u16*   fb = fh + (size_t)n * HW * CF + g * 8;

    float acc[8];
#pragma unroll
    for (int o = 0; o < 8; ++o) acc[o] = 0.f;

#pragma unroll
    for (int k = 0; k < 9; ++k) {
        float dy = ob[(size_t)(g * 18 + 2 * k    ) * HW + pix];
        float dx = ob[(size_t)(g * 18 + 2 * k + 1) * HW + pix];
        float m  = (float)b16f(mb[(size_t)(g * 9 + k) * HW + pix]);

        float py = dy + (float)(k / 3 - 1) + (float)h;
        float px = dx + (float)(k % 3 - 1) + (float)wx;
        float y0f = floorf(py), x0f = floorf(px);
        float ly = py - y0f, lx = px - x0f;
        int y0 = (int)y0f, x0 = (int)x0f;
        int y1 = y0 + 1,   x1 = x0 + 1;

        bool vy0 = (y0 >= 0) && (y0 < HDIM);
        bool vy1 = (y1 >= 0) && (y1 < HDIM);
        bool vx0 = (x0 >= 0) && (x0 < WDIM);
        bool vx1 = (x1 >= 0) && (x1 < WDIM);

        float w00 = (vy0 && vx0) ? (1.f - ly) * (1.f - lx) : 0.f;
        float w01 = (vy0 && vx1) ? (1.f - ly) * lx         : 0.f;
        float w10 = (vy1 && vx0) ? ly * (1.f - lx)         : 0.f;
        float w11 = (vy1 && vx1) ? ly * lx                 : 0.f;

        int y0c = min(max(y0, 0), HDIM - 1), y1c = min(max(y1, 0), HDIM - 1);
        int x0c = min(max(x0, 0), WDIM - 1), x1c = min(max(x1, 0), WDIM - 1);

        f16x8 C00 = *(const f16x8*)(fb + (size_t)(y0c * WDIM + x0c) * CF);
        f16x8 C01 = *(const f16x8*)(fb + (size_t)(y0c * WDIM + x1c) * CF);
        f16x8 C10 = *(const f16x8*)(fb + (size_t)(y1c * WDIM + x0c) * CF);
        f16x8 C11 = *(const f16x8*)(fb + (size_t)(y1c * WDIM + x1c) * CF);

#pragma unroll
        for (int c = 0; c < 8; ++c) {
            float v =      w00 * (float)C00[c];
            v = fmaf(w01, (float)C01[c], v);
            v = fmaf(w10, (float)C10[c], v);
            v = fmaf(w11, (float)C11[c], v);
            v *= m;
            const float* w8 = wg + (k * 8 + c) * 8;   // uniform, contiguous
#pragma unroll
            for (int o = 0; o < 8; ++o)
                acc[o] = fmaf(w8[o], v, acc[o]);
        }
    }

    if (LAST) {
#pragma unroll
        for (int o = 0; o < 8; ++o)
            out32[((size_t)n * CF + g * 8 + o) * HW + pix] = acc[o] + bias[g * 8 + o];
    } else {
        u16 hb[8], lb[8];
#pragma unroll
        for (int o = 0; o < 8; ++o)
            split16(acc[o] + bias[g * 8 + o], hb[o], lb[o]);
        size_t b = ((size_t)n * HW + pix) * CF + g * 8;
        uint4 hv, lv;
        hv.x = (u32)hb[0] | ((u32)hb[1] << 16); hv.y = (u32)hb[2] | ((u32)hb[3] << 16);
        hv.z = (u32)hb[4] | ((u32)hb[5] << 16); hv.w = (u32)hb[6] | ((u32)hb[7] << 16);
        lv.x = (u32)lb[0] | ((u32)lb[1] << 16); lv.y = (u32)lb[2] | ((u32)lb[3] << 16);
        lv.z = (u32)lb[4] | ((u32)lb[5] << 16); lv.w = (u32)lb[6] | ((u32)lb[7] << 16);
        *(uint4*)(out_h + b) = hv;
        *(uint4*)(out_l + b) = lv;
    }
}

// ---------------------------------------------------------------------------
extern "C" void kernel_launch(void* const* d_in, const int* in_sizes, int n_in,
                              void* d_out, int out_size, void* d_ws, size_t ws_size,
                              hipStream_t stream) {
    const float* burst = (const float*)d_in[0];
    const float* bw    = (const float*)d_in[1];

    const float* ow[4]; const float* dw[4]; const float* db[4];
    bool interleaved = (in_sizes[3] == 64 * 8 * 9);
    for (int i = 0; i < 4; ++i) {
        if (interleaved) {
            ow[i] = (const float*)d_in[2 + 3 * i];
            dw[i] = (const float*)d_in[3 + 3 * i];
            db[i] = (const float*)d_in[4 + 3 * i];
        } else {
            ow[i] = (const float*)d_in[2 + i];
            dw[i] = (const float*)d_in[6 + i];
            db[i] = (const float*)d_in[10 + i];
        }
    }

    float* out = (float*)d_out;

    // ws layout (74.4 MB total, <= round-2's proven 74.3+eps usage)
    float* offs    = (float*)d_ws;                   // 10,616,832 f32 (42.5MB)
    u16*   mask    = (u16*)(offs + 10616832);        //  5,308,416 u16
    u16*   featB_h = mask + 5308416;                 //  4,718,592 u16
    u16*   featB_l = featB_h + 4718592;              //  4,718,592 u16
    u16*   wp      = featB_l + 4718592;              //  1,179,648 u16
    float* dwp     = (float*)(wp + 1179648);         //     18,432 f32
    // cat aliases the offs region (dead before first offs write)
    u16*   cat_h   = (u16*)d_ws;                     //  9,437,184 u16
    u16*   cat_l   = cat_h + 9437184;                //  9,437,184 u16
    // featA aliases d_out (dead before the final fp32 write)
    u16*   featA_h = (u16*)d_out;                    //  4,718,592 u16
    u16*   featA_l = featA_h + 4718592;

    const u16* wp_bh = wp;
    const u16* wp_bl = wp + 73728;
    const u16* wp_oh[4], * wp_ol[4];
    for (int i = 0; i < 4; ++i) {
        wp_oh[i] = wp + 147456 + (size_t)i * 258048;
        wp_ol[i] = wp_oh[i] + 129024;
    }

    pack_w_k<<<dim3(512), dim3(256), 0, stream>>>(
        bw, ow[0], ow[1], ow[2], ow[3], dw[0], dw[1], dw[2], dw[3], wp, dwp);
    prep_cat_k<<<dim3(36, NIMG), dim3(256), 0, stream>>>(burst, cat_h, cat_l);

    // bottleneck -> featA (d_out alias)
    conv_mfma_k<128, 0><<<dim3(36, 2, NIMG), dim3(256), 0, stream>>>(
        cat_h, cat_l, wp_bh, wp_bl, nullptr, nullptr, featA_h, featA_l);

    // ping-pong: A -> B -> A -> B -> d_out(fp32)
    u16* fx_h = featA_h; u16* fx_l = featA_l;
    u16* fy_h = featB_h; u16* fy_l = featB_l;
    for (int i = 0; i < 4; ++i) {
        conv_mfma_k<64, 1><<<dim3(36, 7, NIMG), dim3(256), 0, stream>>>(
            fx_h, fx_l, wp_oh[i], wp_ol[i], offs, mask, nullptr, nullptr);
        if (i < 3) {
            deform_k<0><<<dim3(36, 8, NIMG), dim3(256), 0, stream>>>(
                fx_h, offs, mask, dwp + (size_t)i * 4608, db[i], fy_h, fy_l, nullptr);
            u16* th = fx_h; u16* tl = fx_l;
            fx_h = fy_h; fx_l = fy_l; fy_h = th; fy_l = tl;
        } else {
            deform_k<1><<<dim3(36, 8, NIMG), dim3(256), 0, stream>>>(
                fx_h, offs, mask, dwp + (size_t)i * 4608, db[i], nullptr, nullptr, out);
        }
    }
}